// Round 2
// baseline (852.638 us; speedup 1.0000x reference)
//
#include <hip/hip_runtime.h>
#include <hip/hip_bf16.h>

// AttentiveGraph: B=4, N=10000, E=160000, C=F=128, 3 iterations.
//
// Storage-dtype-agnostic: a device probe on `objects` decides fp32 vs bf16
// storage (flag in ws); inputs are canonicalized to bf16, output written per
// flag. Round-1 NaN proved fp32-as-bf16 misread (garbage exponents -> exp ->
// Inf -> Inf*0), so fp32 storage is expected; bf16 path kept as insurance.
//
// Pipeline per call:
//   detect flag; convert objects->bf16, weights->bf16 transposed, biases->f32
//   CSR build (counts -> scan -> fill); no atomics in hot loops afterwards
//   states = tanh(objects @ Wo + b)                       [MFMA]
//   3x:
//     aW = states @ Wa (fp32); EL = exp(states @ Wla + ab) [MFMA, fused]
//     edge gather per node (exp factored out of both sums):
//        S1 = sum EL[dst]; S2 = sum EL[dst]*S[dst]
//        inv = 1/(1+exp(aW)*S1); lg = exp(aW)*S2*inv; sa = S*inv
//     states = tanh(sa + lg @ Wl + b)                     [MFMA] -> d_out
//
#define BATCH 4
#define NNODE 10000
#define NEDGE 160000
#define TWOE  (2*NEDGE)
#define MROWS (BATCH*NNODE)   // 40000

typedef unsigned short u16;
typedef unsigned int   u32;
typedef unsigned long long u64;
typedef __attribute__((ext_vector_type(8))) short bf16x8_t;
typedef __attribute__((ext_vector_type(4))) float f32x4_t;

__device__ __forceinline__ float b2f(u16 h){ return __uint_as_float(((u32)h) << 16); }
__device__ __forceinline__ u16 f2bf(float f){
  u32 u = __float_as_uint(f);
  return (u16)((u + 0x7fffu + ((u >> 16) & 1u)) >> 16);   // RNE
}

// ---------------- storage dtype probe ----------------------------------------
// Examine first 1024 u32 words of objects (~N(0,1) values).
//   fp32 full-precision: low u16 = random mantissa bits -> exponent field
//     uniform -> many hits >=160 (bf16 value >= 2^33: impossible for N(0,1)).
//   fp32 bf16-quantized: low u16 == 0 always.
//   bf16 storage: low u16 is a valid small bf16: no high exponents, not zero.
__global__ void detect_dtype(const u32* __restrict__ objw, int* __restrict__ flag){
  __shared__ int zc, hc;
  if (threadIdx.x == 0){ zc = 0; hc = 0; }
  __syncthreads();
  int z = 0, h = 0;
  for (int i = threadIdx.x; i < 1024; i += 256){
    u32 lo = objw[i] & 0xffffu;
    if (lo == 0) z++;
    if (((lo >> 7) & 0xffu) >= 160u) h++;
  }
  atomicAdd(&zc, z); atomicAdd(&hc, h);
  __syncthreads();
  if (threadIdx.x == 0) *flag = (hc > 0 || zc > 512) ? 1 : 0;   // 1 = fp32 storage
}

// ---------------- input canonicalization -------------------------------------
__global__ void conv_obj(const void* __restrict__ raw, const int* __restrict__ flag,
                         u16* __restrict__ dst){
  int i4 = (blockIdx.x * 256 + threadIdx.x) * 4;   // 4 elems/thread, 5.12M total
  if (*flag){
    float4 f = *(const float4*)((const float*)raw + i4);
    u64 p = (u64)f2bf(f.x) | ((u64)f2bf(f.y) << 16) | ((u64)f2bf(f.z) << 32) | ((u64)f2bf(f.w) << 48);
    *(u64*)(dst + i4) = p;
  } else {
    *(u64*)(dst + i4) = *(const u64*)((const u16*)raw + i4);
  }
}

// Wt[m][c*128+k] = W_m[k*128+c]  (bf16, transposed for B-fragment reads)
__global__ void prep_weights(const void* __restrict__ Wo, const void* __restrict__ Wa,
                             const void* __restrict__ Wla, const void* __restrict__ Wl,
                             const int* __restrict__ flag, u16* __restrict__ Wt){
  int idx = blockIdx.x * 256 + threadIdx.x;       // [0, 4*16384)
  int m = idx >> 14, k = (idx >> 7) & 127, c = idx & 127;
  const void* src = (m == 0) ? Wo : (m == 1) ? Wa : (m == 2) ? Wla : Wl;
  u16 h = (*flag) ? f2bf(((const float*)src)[k * 128 + c])
                  : ((const u16*)src)[k * 128 + c];
  Wt[m * 16384 + c * 128 + k] = h;
}

// biasf[0..127] = state_b (fp32); biasf[128..255] = attention_b
__global__ void conv_bias(const void* __restrict__ ab, const void* __restrict__ sb,
                          const int* __restrict__ flag, float* __restrict__ biasf){
  int t = threadIdx.x;
  bool f = (*flag != 0);
  const void* src = (t < 128) ? sb : ab;
  int i = t & 127;
  biasf[t] = f ? ((const float*)src)[i] : b2f(((const u16*)src)[i]);
}

// ---------------- CSR build ---------------------------------------------------
__global__ void count_edges(const int* __restrict__ conn, int* __restrict__ counts){
  int idx = blockIdx.x * 256 + threadIdx.x;       // [0, BATCH*TWOE)
  int b = idx / TWOE; int e = idx - b * TWOE;
  const int* cp = conn + (size_t)b * NEDGE * 2;
  int src = (e < NEDGE) ? cp[e * 2] : cp[(e - NEDGE) * 2 + 1];
  atomicAdd(&counts[b * NNODE + src], 1);
}

__global__ void scan_kernel(const int* __restrict__ counts, int* __restrict__ row_start,
                            int* __restrict__ cursor){
  int b = blockIdx.x;
  __shared__ int buf[256];
  __shared__ int s_carry;
  if (threadIdx.x == 0) s_carry = 0;
  __syncthreads();
  for (int base = 0; base < NNODE; base += 256){
    int n = base + (int)threadIdx.x;
    int v = (n < NNODE) ? counts[b * NNODE + n] : 0;
    buf[threadIdx.x] = v;
    __syncthreads();
    for (int off = 1; off < 256; off <<= 1){
      int x = (threadIdx.x >= (unsigned)off) ? buf[threadIdx.x - off] : 0;
      __syncthreads();
      buf[threadIdx.x] += x;
      __syncthreads();
    }
    int incl  = buf[threadIdx.x];
    int carry = s_carry;
    if (n < NNODE){
      int start = carry + incl - v;
      row_start[b * (NNODE + 1) + n] = start;
      cursor[b * NNODE + n] = start;
    }
    __syncthreads();
    if (threadIdx.x == 255) s_carry = carry + incl;
    __syncthreads();
  }
  if (threadIdx.x == 0) row_start[b * (NNODE + 1) + NNODE] = s_carry;
}

__global__ void fill_edges(const int* __restrict__ conn, int* __restrict__ cursor,
                           int* __restrict__ edge_dst){
  int idx = blockIdx.x * 256 + threadIdx.x;
  int b = idx / TWOE; int e = idx - b * TWOE;
  const int* cp = conn + (size_t)b * NEDGE * 2;
  int src, dst;
  if (e < NEDGE){ src = cp[e * 2];               dst = cp[e * 2 + 1]; }
  else          { src = cp[(e - NEDGE) * 2 + 1]; dst = cp[(e - NEDGE) * 2]; }
  int pos = atomicAdd(&cursor[b * NNODE + src], 1);
  edge_dst[(size_t)b * TWOE + pos] = dst;
}

// ---------------- MFMA GEMMs (M=40000, N=K=128), no LDS -----------------------
// wave: 16 rows x 128 cols; block 4 waves = 64 rows.
// A-frag: row=lane&15, k=(lane>>4)*8+j (16B contiguous bf16 load).
// B-frag from Wt (transposed): col=lane&15, k=(lane>>4)*8+j.
// D-frag: row=(lane>>4)*4+i, col=lane&15  [verified m89/m91].

__global__ void __launch_bounds__(256) init_gemm(const u16* __restrict__ obj,
    const u16* __restrict__ Wt, const float* __restrict__ biasf,
    u16* __restrict__ states_bf, u16* __restrict__ gat){
  const int lane = threadIdx.x & 63, wave = threadIdx.x >> 6;
  const int r0 = blockIdx.x * 64 + wave * 16;
  const int lm = lane & 15, lq = lane >> 4;
  f32x4_t acc[8];
  #pragma unroll
  for (int i = 0; i < 8; i++) acc[i] = (f32x4_t){0.f, 0.f, 0.f, 0.f};
  const u16* arow = obj + (size_t)(r0 + lm) * 128 + lq * 8;
  #pragma unroll
  for (int ks = 0; ks < 4; ks++){
    bf16x8_t a = *(const bf16x8_t*)(arow + ks * 32);
    #pragma unroll
    for (int nb = 0; nb < 8; nb++){
      bf16x8_t bf = *(const bf16x8_t*)(Wt + (nb * 16 + lm) * 128 + ks * 32 + lq * 8);
      acc[nb] = __builtin_amdgcn_mfma_f32_16x16x32_bf16(a, bf, acc[nb], 0, 0, 0);
    }
  }
  #pragma unroll
  for (int nb = 0; nb < 8; nb++){
    int col = nb * 16 + lm;
    float bb = biasf[col];
    #pragma unroll
    for (int i = 0; i < 4; i++){
      int row = r0 + lq * 4 + i;
      u16 h = f2bf(tanhf(acc[nb][i] + bb));
      states_bf[(size_t)row * 128 + col] = h;
      gat[(size_t)row * 256 + (col >> 1) * 4 + 2 + (col & 1)] = h;   // S slot
    }
  }
}

__global__ void __launch_bounds__(256) gemm_aw_law(const u16* __restrict__ sbf,
    const u16* __restrict__ Wt, const float* __restrict__ biasf,
    float* __restrict__ awsa /*aW out, fp32*/, u16* __restrict__ gat){
  const int lane = threadIdx.x & 63, wave = threadIdx.x >> 6;
  const int r0 = blockIdx.x * 64 + wave * 16;
  const int lm = lane & 15, lq = lane >> 4;
  const u16* Wta  = Wt + 16384;
  const u16* Wtla = Wt + 32768;
  f32x4_t accA[8], accL[8];
  #pragma unroll
  for (int i = 0; i < 8; i++){ accA[i] = (f32x4_t){0.f,0.f,0.f,0.f}; accL[i] = (f32x4_t){0.f,0.f,0.f,0.f}; }
  const u16* arow = sbf + (size_t)(r0 + lm) * 128 + lq * 8;
  #pragma unroll
  for (int ks = 0; ks < 4; ks++){
    bf16x8_t a = *(const bf16x8_t*)(arow + ks * 32);
    #pragma unroll
    for (int nb = 0; nb < 8; nb++){
      bf16x8_t ba = *(const bf16x8_t*)(Wta  + (nb * 16 + lm) * 128 + ks * 32 + lq * 8);
      bf16x8_t bl = *(const bf16x8_t*)(Wtla + (nb * 16 + lm) * 128 + ks * 32 + lq * 8);
      accA[nb] = __builtin_amdgcn_mfma_f32_16x16x32_bf16(a, ba, accA[nb], 0, 0, 0);
      accL[nb] = __builtin_amdgcn_mfma_f32_16x16x32_bf16(a, bl, accL[nb], 0, 0, 0);
    }
  }
  #pragma unroll
  for (int nb = 0; nb < 8; nb++){
    int col = nb * 16 + lm;
    float bb = biasf[128 + col];
    #pragma unroll
    for (int i = 0; i < 4; i++){
      int row = r0 + lq * 4 + i;
      awsa[(size_t)row * 128 + col] = accA[nb][i];
      gat[(size_t)row * 256 + (col >> 1) * 4 + (col & 1)] = f2bf(__expf(accL[nb][i] + bb));  // EL slot
    }
  }
}

// ---------------- edge gather: 1 wave per node --------------------------------
// gat row (512B): per lane t: {EL[2t], EL[2t+1], S[2t], S[2t+1]} -> one 8B load/edge.
__global__ void __launch_bounds__(256) edge_kernel(float* awsa,
    const u16* __restrict__ gat, const u16* __restrict__ states_bf,
    const int* __restrict__ row_start, const int* __restrict__ edge_dst,
    u16* __restrict__ lgb){
  int node = blockIdx.x * 4 + (threadIdx.x >> 6);
  int lane = threadIdx.x & 63;
  int b = node / NNODE;
  int n = node - b * NNODE;
  int e0 = row_start[b * (NNODE + 1) + n];
  int e1 = row_start[b * (NNODE + 1) + n + 1];
  const int* ed = edge_dst + (size_t)b * TWOE;
  const u16* gatb = gat + (size_t)b * NNODE * 256;

  float2 aw = *(const float2*)(awsa + (size_t)node * 128 + 2 * lane);
  float ea0 = __expf(aw.x), ea1 = __expf(aw.y);
  float s1x = 0.f, s1y = 0.f, s2x = 0.f, s2y = 0.f;
  for (int e = e0; e < e1; e++){
    int d = ed[e];
    uint2 g = *(const uint2*)(gatb + (size_t)d * 256 + lane * 4);
    float el0 = __uint_as_float(g.x << 16);
    float el1 = __uint_as_float(g.x & 0xffff0000u);
    float sv0 = __uint_as_float(g.y << 16);
    float sv1 = __uint_as_float(g.y & 0xffff0000u);
    s1x += el0; s1y += el1;
    s2x = fmaf(el0, sv0, s2x); s2y = fmaf(el1, sv1, s2y);
  }
  float inv0 = 1.0f / (1.0f + ea0 * s1x);
  float inv1 = 1.0f / (1.0f + ea1 * s1y);
  float lg0 = ea0 * s2x * inv0;
  float lg1 = ea1 * s2y * inv1;
  u32 sp = ((const u32*)states_bf)[(size_t)node * 64 + lane];
  float s0 = __uint_as_float(sp << 16);
  float s1 = __uint_as_float(sp & 0xffff0000u);
  float2 sav; sav.x = s0 * inv0; sav.y = s1 * inv1;
  *(float2*)(awsa + (size_t)node * 128 + 2 * lane) = sav;          // sa reuses aW buffer
  ((u32*)lgb)[(size_t)node * 64 + lane] = (u32)f2bf(lg0) | ((u32)f2bf(lg1) << 16);
}

__global__ void __launch_bounds__(256) gemm_out(const u16* __restrict__ lgb,
    const u16* __restrict__ Wt, const float* __restrict__ sa, const float* __restrict__ biasf,
    const int* __restrict__ flag, u16* __restrict__ states_bf, u16* __restrict__ gat,
    void* __restrict__ outp){
  const int lane = threadIdx.x & 63, wave = threadIdx.x >> 6;
  const int r0 = blockIdx.x * 64 + wave * 16;
  const int lm = lane & 15, lq = lane >> 4;
  const u16* Wtl = Wt + 49152;
  bool f32out = (*flag != 0);
  f32x4_t acc[8];
  #pragma unroll
  for (int i = 0; i < 8; i++) acc[i] = (f32x4_t){0.f, 0.f, 0.f, 0.f};
  const u16* arow = lgb + (size_t)(r0 + lm) * 128 + lq * 8;
  #pragma unroll
  for (int ks = 0; ks < 4; ks++){
    bf16x8_t a = *(const bf16x8_t*)(arow + ks * 32);
    #pragma unroll
    for (int nb = 0; nb < 8; nb++){
      bf16x8_t bf = *(const bf16x8_t*)(Wtl + (nb * 16 + lm) * 128 + ks * 32 + lq * 8);
      acc[nb] = __builtin_amdgcn_mfma_f32_16x16x32_bf16(a, bf, acc[nb], 0, 0, 0);
    }
  }
  #pragma unroll
  for (int nb = 0; nb < 8; nb++){
    int col = nb * 16 + lm;
    float bb = biasf[col];
    #pragma unroll
    for (int i = 0; i < 4; i++){
      int row = r0 + lq * 4 + i;
      float v = tanhf(sa[(size_t)row * 128 + col] + acc[nb][i] + bb);
      u16 h = f2bf(v);
      states_bf[(size_t)row * 128 + col] = h;
      gat[(size_t)row * 256 + (col >> 1) * 4 + 2 + (col & 1)] = h;   // S slot
      if (f32out) ((float*)outp)[(size_t)row * 128 + col] = v;
      else        ((u16*)  outp)[(size_t)row * 128 + col] = h;
    }
  }
}

// ---------------- host launcher ----------------------------------------------
extern "C" void kernel_launch(void* const* d_in, const int* in_sizes, int n_in,
                              void* d_out, int out_size, void* d_ws, size_t ws_size,
                              hipStream_t stream){
  (void)in_sizes; (void)n_in; (void)ws_size; (void)out_size;
  const void* objects = d_in[0];
  const void* Wo      = d_in[1];
  const void* Wa      = d_in[2];
  const void* Wla     = d_in[3];
  const void* attn_b  = d_in[4];
  const void* Wl      = d_in[5];
  const void* state_b = d_in[6];
  const int*  conn    = (const int*)d_in[7];

  char* base = (char*)d_ws;
  size_t off = 0;
  auto alloc = [&](size_t bytes) -> char* {
    char* p = base + off;
    off = (off + bytes + 255) & ~(size_t)255;
    return p;
  };
  int*   flag      = (int*)  alloc(256);
  u16*   Wt        = (u16*)  alloc((size_t)4 * 16384 * 2);      // bf16 transposed weights
  float* biasf     = (float*)alloc(256 * 4);
  u16*   states_bf = (u16*)  alloc((size_t)MROWS * 128 * 2);
  float* awsa      = (float*)alloc((size_t)MROWS * 128 * 4);    // aW fp32, reused as sa
  u16*   gat       = (u16*)  alloc((size_t)MROWS * 512);        // {EL pair, S pair} per lane
  u16*   lgb       = (u16*)  alloc((size_t)MROWS * 128 * 2);    // also obj_bf before iter 0
  int*   counts    = (int*)  alloc((size_t)MROWS * 4);
  int*   cursor    = (int*)  alloc((size_t)MROWS * 4);
  int*   row_start = (int*)  alloc((size_t)BATCH * (NNODE + 1) * 4);
  int*   edge_dst  = (int*)  alloc((size_t)BATCH * TWOE * 4);
  u16*   obj_bf    = lgb;    // alias: obj_bf consumed by init_gemm before lgb written

  detect_dtype<<<1, 256, 0, stream>>>((const u32*)objects, flag);
  conv_obj<<<MROWS * 128 / 4 / 256, 256, 0, stream>>>(objects, flag, obj_bf);
  prep_weights<<<256, 256, 0, stream>>>(Wo, Wa, Wla, Wl, flag, Wt);
  conv_bias<<<1, 256, 0, stream>>>(attn_b, state_b, flag, biasf);

  hipMemsetAsync(counts, 0, (size_t)MROWS * 4, stream);
  count_edges<<<(BATCH * TWOE) / 256, 256, 0, stream>>>(conn, counts);
  scan_kernel<<<BATCH, 256, 0, stream>>>(counts, row_start, cursor);
  fill_edges<<<(BATCH * TWOE) / 256, 256, 0, stream>>>(conn, cursor, edge_dst);

  init_gemm<<<MROWS / 64, 256, 0, stream>>>(obj_bf, Wt, biasf, states_bf, gat);
  for (int it = 0; it < 3; it++){
    gemm_aw_law<<<MROWS / 64, 256, 0, stream>>>(states_bf, Wt, biasf, awsa, gat);
    edge_kernel<<<MROWS / 4, 256, 0, stream>>>(awsa, gat, states_bf, row_start, edge_dst, lgb);
    gemm_out<<<MROWS / 64, 256, 0, stream>>>(lgb, Wt, awsa, biasf, flag, states_bf, gat, d_out);
  }
}

// Round 3
// 534.740 us; speedup vs baseline: 1.5945x; 1.5945x over previous
//
#include <hip/hip_runtime.h>
#include <hip/hip_bf16.h>

// AttentiveGraph: B=4, N=10000, E=160000, C=F=128, 3 iterations.
// R3: edge kernel x8-unroll MLP + scalarized indices + XCD-batch swizzle;
// fused GEMMs (out+aw/law via LDS transpose); states_bf eliminated (self-S
// read from gat row); sa stored fp16 in back half of aW region; d_out written
// only by final kernel; hierarchical CSR scan.

#define BATCH 4
#define NNODE 10000
#define NEDGE 160000
#define TWOE  (2*NEDGE)
#define MROWS (BATCH*NNODE)   // 40000

typedef unsigned short u16;
typedef unsigned int   u32;
typedef unsigned long long u64;
typedef __attribute__((ext_vector_type(8))) short bf16x8_t;
typedef __attribute__((ext_vector_type(4))) float f32x4_t;

__device__ __forceinline__ float b2f(u16 h){ return __uint_as_float(((u32)h) << 16); }
__device__ __forceinline__ u16 f2bf(float f){
  u32 u = __float_as_uint(f);
  return (u16)((u + 0x7fffu + ((u >> 16) & 1u)) >> 16);   // RNE
}
__device__ __forceinline__ float fast_tanh(float x){
  float e = __expf(2.0f * x);                      // v_exp_f32 based
  return fmaf(-2.0f, __builtin_amdgcn_rcpf(e + 1.0f), 1.0f);
}

// ---------------- storage dtype probe (fp32 vs bf16 storage) ------------------
__global__ void detect_dtype(const u32* __restrict__ objw, int* __restrict__ flag){
  __shared__ int zc, hc;
  if (threadIdx.x == 0){ zc = 0; hc = 0; }
  __syncthreads();
  int z = 0, h = 0;
  for (int i = threadIdx.x; i < 1024; i += 256){
    u32 lo = objw[i] & 0xffffu;
    if (lo == 0) z++;
    if (((lo >> 7) & 0xffu) >= 160u) h++;
  }
  atomicAdd(&zc, z); atomicAdd(&hc, h);
  __syncthreads();
  if (threadIdx.x == 0) *flag = (hc > 0 || zc > 512) ? 1 : 0;   // 1 = fp32 storage
}

// ---------------- input canonicalization -------------------------------------
__global__ void conv_obj(const void* __restrict__ raw, const int* __restrict__ flag,
                         u16* __restrict__ dst){
  int i4 = (blockIdx.x * 256 + threadIdx.x) * 4;
  if (*flag){
    float4 f = *(const float4*)((const float*)raw + i4);
    u64 p = (u64)f2bf(f.x) | ((u64)f2bf(f.y) << 16) | ((u64)f2bf(f.z) << 32) | ((u64)f2bf(f.w) << 48);
    *(u64*)(dst + i4) = p;
  } else {
    *(u64*)(dst + i4) = *(const u64*)((const u16*)raw + i4);
  }
}

// Wt[m][c*128+k] = W_m[k*128+c]; tail block converts biases.
__global__ void prep_weights(const void* __restrict__ Wo, const void* __restrict__ Wa,
                             const void* __restrict__ Wla, const void* __restrict__ Wl,
                             const void* __restrict__ ab, const void* __restrict__ sb,
                             const int* __restrict__ flag, u16* __restrict__ Wt,
                             float* __restrict__ biasf){
  int idx = blockIdx.x * 256 + threadIdx.x;
  bool f = (*flag != 0);
  if (idx < 65536){
    int m = idx >> 14, k = (idx >> 7) & 127, c = idx & 127;
    const void* src = (m == 0) ? Wo : (m == 1) ? Wa : (m == 2) ? Wla : Wl;
    u16 h = f ? f2bf(((const float*)src)[k * 128 + c]) : ((const u16*)src)[k * 128 + c];
    Wt[m * 16384 + c * 128 + k] = h;
  } else {
    int t = idx - 65536;                     // 0..255
    const void* src = (t < 128) ? sb : ab;
    int i = t & 127;
    biasf[t] = f ? ((const float*)src)[i] : b2f(((const u16*)src)[i]);
  }
}

// ---------------- CSR build ---------------------------------------------------
__global__ void count_edges(const int* __restrict__ conn, int* __restrict__ counts){
  int idx = blockIdx.x * 256 + threadIdx.x;       // [0, BATCH*NEDGE)
  int b = idx / NEDGE; int e = idx - b * NEDGE;
  int2 c = ((const int2*)conn)[(size_t)b * NEDGE + e];
  atomicAdd(&counts[b * NNODE + c.x], 1);
  atomicAdd(&counts[b * NNODE + c.y], 1);
}

// scanA: per 256-node chunk local exclusive scan + chunk totals. 160 blocks.
__global__ void scanA(const int* __restrict__ counts, int* __restrict__ row_start,
                      int* __restrict__ bsum){
  int b = blockIdx.x / 40, j = blockIdx.x % 40;
  int n = j * 256 + threadIdx.x;
  __shared__ int buf[256];
  int v = (n < NNODE) ? counts[b * NNODE + n] : 0;
  buf[threadIdx.x] = v;
  __syncthreads();
  for (int off = 1; off < 256; off <<= 1){
    int x = (threadIdx.x >= (unsigned)off) ? buf[threadIdx.x - off] : 0;
    __syncthreads();
    buf[threadIdx.x] += x;
    __syncthreads();
  }
  int incl = buf[threadIdx.x];
  if (n < NNODE) row_start[b * (NNODE + 1) + n] = incl - v;
  if (threadIdx.x == 255) bsum[blockIdx.x] = incl;
}

// scanB: offsets across 40 chunks per batch. 1 block.
__global__ void scanB(const int* __restrict__ bsum, int* __restrict__ boff,
                      int* __restrict__ row_start){
  __shared__ int s[160];
  if (threadIdx.x < 160) s[threadIdx.x] = bsum[threadIdx.x];
  __syncthreads();
  if (threadIdx.x < 160){
    int b = threadIdx.x / 40, j = threadIdx.x % 40;
    int off = 0;
    for (int q = b * 40; q < b * 40 + j; q++) off += s[q];
    boff[threadIdx.x] = off;
  }
  if (threadIdx.x < BATCH) row_start[threadIdx.x * (NNODE + 1) + NNODE] = TWOE;
}

// scanC: finalize row_start, init cursor. 160 blocks.
__global__ void scanC(int* __restrict__ row_start, const int* __restrict__ boff,
                      int* __restrict__ cursor){
  int b = blockIdx.x / 40, j = blockIdx.x % 40;
  int n = j * 256 + threadIdx.x;
  if (n < NNODE){
    int idx = b * (NNODE + 1) + n;
    int r = row_start[idx] + boff[blockIdx.x];
    row_start[idx] = r;
    cursor[b * NNODE + n] = r;
  }
}

__global__ void fill_edges(const int* __restrict__ conn, int* __restrict__ cursor,
                           int* __restrict__ edge_dst){
  int idx = blockIdx.x * 256 + threadIdx.x;
  int b = idx / NEDGE; int e = idx - b * NEDGE;
  int2 c = ((const int2*)conn)[(size_t)b * NEDGE + e];
  int p1 = atomicAdd(&cursor[b * NNODE + c.x], 1);
  edge_dst[(size_t)b * TWOE + p1] = c.y;
  int p2 = atomicAdd(&cursor[b * NNODE + c.y], 1);
  edge_dst[(size_t)b * TWOE + p2] = c.x;
}

// ---------------- MFMA helpers (wave = 16 rows x 128 cols) --------------------
__device__ __forceinline__ void gemm_tile(const u16* __restrict__ arow,
    const u16* __restrict__ wt, int lm, int lq, f32x4_t acc[8]){
  #pragma unroll
  for (int ks = 0; ks < 4; ks++){
    bf16x8_t a = *(const bf16x8_t*)(arow + ks * 32);
    #pragma unroll
    for (int nb = 0; nb < 8; nb++){
      bf16x8_t bfr = *(const bf16x8_t*)(wt + (nb * 16 + lm) * 128 + ks * 32 + lq * 8);
      acc[nb] = __builtin_amdgcn_mfma_f32_16x16x32_bf16(a, bfr, acc[nb], 0, 0, 0);
    }
  }
}

// phase 2: states tile (in LDS, A-layout readable) -> aW (fp32) + EL (gat slot)
__device__ __forceinline__ void phase2_awlaw(const u16* __restrict__ ldsrow,
    const u16* __restrict__ Wt, const float* __restrict__ biasf,
    int lm, int lq, int r0, float* __restrict__ awsa, u16* __restrict__ gat){
  const u16* Wta  = Wt + 16384;
  const u16* Wtla = Wt + 32768;
  f32x4_t accA[8], accL[8];
  #pragma unroll
  for (int i = 0; i < 8; i++){ accA[i] = (f32x4_t){0.f,0.f,0.f,0.f}; accL[i] = (f32x4_t){0.f,0.f,0.f,0.f}; }
  #pragma unroll
  for (int ks = 0; ks < 4; ks++){
    bf16x8_t a = *(const bf16x8_t*)(ldsrow + ks * 32);
    #pragma unroll
    for (int nb = 0; nb < 8; nb++){
      bf16x8_t ba = *(const bf16x8_t*)(Wta  + (nb * 16 + lm) * 128 + ks * 32 + lq * 8);
      bf16x8_t bl = *(const bf16x8_t*)(Wtla + (nb * 16 + lm) * 128 + ks * 32 + lq * 8);
      accA[nb] = __builtin_amdgcn_mfma_f32_16x16x32_bf16(a, ba, accA[nb], 0, 0, 0);
      accL[nb] = __builtin_amdgcn_mfma_f32_16x16x32_bf16(a, bl, accL[nb], 0, 0, 0);
    }
  }
  #pragma unroll
  for (int nb = 0; nb < 8; nb++){
    int col = nb * 16 + lm;
    float bb = biasf[128 + col];
    #pragma unroll
    for (int i = 0; i < 4; i++){
      int row = r0 + lq * 4 + i;
      awsa[(size_t)row * 128 + col] = accA[nb][i];
      gat[(size_t)row * 256 + (col >> 1) * 4 + (col & 1)] = f2bf(__expf(accL[nb][i] + bb));
    }
  }
}

// init: states = tanh(obj@Wo + b); then aW/EL for iter 0.
__global__ void __launch_bounds__(256) fused_init(const u16* __restrict__ obj,
    const u16* __restrict__ Wt, const float* __restrict__ biasf,
    float* __restrict__ awsa, u16* __restrict__ gat){
  __shared__ u16 lds[4][16][136];
  const int lane = threadIdx.x & 63, wave = threadIdx.x >> 6;
  const int r0 = blockIdx.x * 64 + wave * 16;
  const int lm = lane & 15, lq = lane >> 4;
  f32x4_t acc[8];
  #pragma unroll
  for (int i = 0; i < 8; i++) acc[i] = (f32x4_t){0.f, 0.f, 0.f, 0.f};
  gemm_tile(obj + (size_t)(r0 + lm) * 128 + lq * 8, Wt, lm, lq, acc);
  #pragma unroll
  for (int nb = 0; nb < 8; nb++){
    int col = nb * 16 + lm;
    float bb = biasf[col];
    #pragma unroll
    for (int i = 0; i < 4; i++){
      int row = r0 + lq * 4 + i;
      u16 h = f2bf(fast_tanh(acc[nb][i] + bb));
      gat[(size_t)row * 256 + (col >> 1) * 4 + 2 + (col & 1)] = h;   // S slot
      lds[wave][lq * 4 + i][col] = h;
    }
  }
  __syncthreads();
  phase2_awlaw(&lds[wave][lm][lq * 8], Wt, biasf, lm, lq, r0, awsa, gat);
}

// mid: states = tanh(sa + lgb@Wl + b); then aW/EL for next iter.
__global__ void __launch_bounds__(256) fused_mid(const u16* __restrict__ lgb,
    const u16* __restrict__ Wt, const float* __restrict__ biasf,
    float* __restrict__ awsa, u16* __restrict__ gat){
  __shared__ u16 lds[4][16][136];
  const int lane = threadIdx.x & 63, wave = threadIdx.x >> 6;
  const int r0 = blockIdx.x * 64 + wave * 16;
  const int lm = lane & 15, lq = lane >> 4;
  const _Float16* sah = (const _Float16*)awsa;   // fp16 sa in back half of aW rows
  f32x4_t acc[8];
  #pragma unroll
  for (int i = 0; i < 8; i++) acc[i] = (f32x4_t){0.f, 0.f, 0.f, 0.f};
  gemm_tile(lgb + (size_t)(r0 + lm) * 128 + lq * 8, Wt + 49152, lm, lq, acc);
  #pragma unroll
  for (int nb = 0; nb < 8; nb++){
    int col = nb * 16 + lm;
    float bb = biasf[col];
    #pragma unroll
    for (int i = 0; i < 4; i++){
      int row = r0 + lq * 4 + i;
      float sa = (float)sah[(size_t)row * 256 + 128 + col];
      u16 h = f2bf(fast_tanh(sa + acc[nb][i] + bb));
      gat[(size_t)row * 256 + (col >> 1) * 4 + 2 + (col & 1)] = h;   // S slot
      lds[wave][lq * 4 + i][col] = h;
    }
  }
  __syncthreads();
  phase2_awlaw(&lds[wave][lm][lq * 8], Wt, biasf, lm, lq, r0, awsa, gat);
}

// final: out = tanh(sa + lgb@Wl + b), fp32 or bf16 per flag.
__global__ void __launch_bounds__(256) final_out(const u16* __restrict__ lgb,
    const u16* __restrict__ Wt, const float* __restrict__ biasf,
    const float* __restrict__ awsa, const int* __restrict__ flag,
    void* __restrict__ outp){
  const int lane = threadIdx.x & 63, wave = threadIdx.x >> 6;
  const int r0 = blockIdx.x * 64 + wave * 16;
  const int lm = lane & 15, lq = lane >> 4;
  const _Float16* sah = (const _Float16*)awsa;
  bool f32out = (*flag != 0);
  f32x4_t acc[8];
  #pragma unroll
  for (int i = 0; i < 8; i++) acc[i] = (f32x4_t){0.f, 0.f, 0.f, 0.f};
  gemm_tile(lgb + (size_t)(r0 + lm) * 128 + lq * 8, Wt + 49152, lm, lq, acc);
  #pragma unroll
  for (int nb = 0; nb < 8; nb++){
    int col = nb * 16 + lm;
    float bb = biasf[col];
    #pragma unroll
    for (int i = 0; i < 4; i++){
      int row = r0 + lq * 4 + i;
      float sa = (float)sah[(size_t)row * 256 + 128 + col];
      float v = fast_tanh(sa + acc[nb][i] + bb);
      if (f32out) ((float*)outp)[(size_t)row * 128 + col] = v;
      else        ((u16*)  outp)[(size_t)row * 128 + col] = f2bf(v);
    }
  }
}

// ---------------- edge gather: 1 wave/node, x8 unroll, XCD-batch swizzle ------
__device__ __forceinline__ void acc_edge(uint2 g, float& s1x, float& s1y,
                                         float& s2x, float& s2y){
  float el0 = __uint_as_float(g.x << 16);
  float el1 = __uint_as_float(g.x & 0xffff0000u);
  float sv0 = __uint_as_float(g.y << 16);
  float sv1 = __uint_as_float(g.y & 0xffff0000u);
  s1x += el0; s1y += el1;
  s2x = fmaf(el0, sv0, s2x);
  s2y = fmaf(el1, sv1, s2y);
}

__global__ void __launch_bounds__(256) edge_kernel(float* __restrict__ awsa,
    const u16* __restrict__ gat, const int* __restrict__ row_start,
    const int* __restrict__ edge_dst, u16* __restrict__ lgb){
  // XCD-pair <-> batch swizzle: blockIdx%8 -> XCD (round-robin dispatch),
  // batch = XCD/2, so each XCD's L2 only sees one batch's 5.1MB gat slab.
  int g = blockIdx.x;
  int xcd = g & 7;
  int b = xcd >> 1;
  int i = ((g >> 3) << 1) | (xcd & 1);            // 0..2499 per batch
  int n = i * 4 + (int)(threadIdx.x >> 6);
  int node = b * NNODE + n;
  int lane = threadIdx.x & 63;
  int e0 = __builtin_amdgcn_readfirstlane(row_start[b * (NNODE + 1) + n]);
  int e1 = __builtin_amdgcn_readfirstlane(row_start[b * (NNODE + 1) + n + 1]);
  const int* ed = edge_dst + (size_t)b * TWOE;
  const u16* gatb = gat + (size_t)b * NNODE * 256;

  float2 aw = *(const float2*)(awsa + (size_t)node * 128 + 2 * lane);
  float ea0 = __expf(aw.x), ea1 = __expf(aw.y);
  float s1x = 0.f, s1y = 0.f, s2x = 0.f, s2y = 0.f;
  float t1x = 0.f, t1y = 0.f, t2x = 0.f, t2y = 0.f;
  int e = e0;
  for (; e + 8 <= e1; e += 8){
    int d0 = ed[e+0], d1 = ed[e+1], d2 = ed[e+2], d3 = ed[e+3];
    int d4 = ed[e+4], d5 = ed[e+5], d6 = ed[e+6], d7 = ed[e+7];
    uint2 g0 = *(const uint2*)(gatb + (size_t)d0 * 256 + lane * 4);
    uint2 g1 = *(const uint2*)(gatb + (size_t)d1 * 256 + lane * 4);
    uint2 g2 = *(const uint2*)(gatb + (size_t)d2 * 256 + lane * 4);
    uint2 g3 = *(const uint2*)(gatb + (size_t)d3 * 256 + lane * 4);
    uint2 g4 = *(const uint2*)(gatb + (size_t)d4 * 256 + lane * 4);
    uint2 g5 = *(const uint2*)(gatb + (size_t)d5 * 256 + lane * 4);
    uint2 g6 = *(const uint2*)(gatb + (size_t)d6 * 256 + lane * 4);
    uint2 g7 = *(const uint2*)(gatb + (size_t)d7 * 256 + lane * 4);
    acc_edge(g0, s1x, s1y, s2x, s2y); acc_edge(g1, t1x, t1y, t2x, t2y);
    acc_edge(g2, s1x, s1y, s2x, s2y); acc_edge(g3, t1x, t1y, t2x, t2y);
    acc_edge(g4, s1x, s1y, s2x, s2y); acc_edge(g5, t1x, t1y, t2x, t2y);
    acc_edge(g6, s1x, s1y, s2x, s2y); acc_edge(g7, t1x, t1y, t2x, t2y);
  }
  for (; e < e1; e++){
    int d = ed[e];
    uint2 gg = *(const uint2*)(gatb + (size_t)d * 256 + lane * 4);
    acc_edge(gg, s1x, s1y, s2x, s2y);
  }
  s1x += t1x; s1y += t1y; s2x += t2x; s2y += t2y;
  float inv0 = __builtin_amdgcn_rcpf(fmaf(ea0, s1x, 1.0f));
  float inv1 = __builtin_amdgcn_rcpf(fmaf(ea1, s1y, 1.0f));
  float lg0 = ea0 * s2x * inv0;
  float lg1 = ea1 * s2y * inv1;
  // self S from own gat row (S pair of lane): byte off node*512 + lane*8 + 4
  u32 sp = *(const u32*)((const u16*)gat + (size_t)node * 256 + lane * 4 + 2);
  float s0 = __uint_as_float(sp << 16);
  float s1 = __uint_as_float(sp & 0xffff0000u);
  _Float16 h0 = (_Float16)(s0 * inv0);
  _Float16 h1 = (_Float16)(s1 * inv1);
  u32 pk = (u32)(*(const u16*)&h0) | ((u32)(*(const u16*)&h1) << 16);
  ((u32*)awsa)[(size_t)node * 128 + 64 + lane] = pk;              // sa fp16, back half
  ((u32*)lgb)[(size_t)node * 64 + lane] = (u32)f2bf(lg0) | ((u32)f2bf(lg1) << 16);
}

// ---------------- host launcher ----------------------------------------------
extern "C" void kernel_launch(void* const* d_in, const int* in_sizes, int n_in,
                              void* d_out, int out_size, void* d_ws, size_t ws_size,
                              hipStream_t stream){
  (void)in_sizes; (void)n_in; (void)ws_size; (void)out_size;
  const void* objects = d_in[0];
  const void* Wo      = d_in[1];
  const void* Wa      = d_in[2];
  const void* Wla     = d_in[3];
  const void* attn_b  = d_in[4];
  const void* Wl      = d_in[5];
  const void* state_b = d_in[6];
  const int*  conn    = (const int*)d_in[7];

  char* base = (char*)d_ws;
  size_t off = 0;
  auto alloc = [&](size_t bytes) -> char* {
    char* p = base + off;
    off = (off + bytes + 255) & ~(size_t)255;
    return p;
  };
  int*   flag      = (int*)  alloc(256);
  u16*   Wt        = (u16*)  alloc((size_t)4 * 16384 * 2);
  float* biasf     = (float*)alloc(256 * 4);
  float* awsa      = (float*)alloc((size_t)MROWS * 128 * 4);   // aW fp32; sa fp16 overlay
  u16*   gat       = (u16*)  alloc((size_t)MROWS * 512);       // {EL pair, S pair} / lane
  u16*   lgb       = (u16*)  alloc((size_t)MROWS * 128 * 2);   // aliased as obj_bf pre-iter0
  int*   counts    = (int*)  alloc((size_t)MROWS * 4);
  int*   cursor    = (int*)  alloc((size_t)MROWS * 4);
  int*   row_start = (int*)  alloc((size_t)BATCH * (NNODE + 1) * 4);
  int*   edge_dst  = (int*)  alloc((size_t)BATCH * TWOE * 4);
  int*   bsum      = (int*)  alloc(160 * 4);
  int*   boff      = (int*)  alloc(160 * 4);
  u16*   obj_bf    = lgb;    // consumed by fused_init before edge writes lgb

  detect_dtype<<<1, 256, 0, stream>>>((const u32*)objects, flag);
  conv_obj<<<MROWS * 128 / 4 / 256, 256, 0, stream>>>(objects, flag, obj_bf);
  prep_weights<<<257, 256, 0, stream>>>(Wo, Wa, Wla, Wl, attn_b, state_b, flag, Wt, biasf);

  hipMemsetAsync(counts, 0, (size_t)MROWS * 4, stream);
  count_edges<<<(BATCH * NEDGE) / 256, 256, 0, stream>>>(conn, counts);
  scanA<<<160, 256, 0, stream>>>(counts, row_start, bsum);
  scanB<<<1, 256, 0, stream>>>(bsum, boff, row_start);
  scanC<<<160, 256, 0, stream>>>(row_start, boff, cursor);
  fill_edges<<<(BATCH * NEDGE) / 256, 256, 0, stream>>>(conn, cursor, edge_dst);

  fused_init<<<MROWS / 64, 256, 0, stream>>>(obj_bf, Wt, biasf, awsa, gat);
  edge_kernel<<<MROWS / 4, 256, 0, stream>>>(awsa, gat, row_start, edge_dst, lgb);
  fused_mid<<<MROWS / 64, 256, 0, stream>>>(lgb, Wt, biasf, awsa, gat);
  edge_kernel<<<MROWS / 4, 256, 0, stream>>>(awsa, gat, row_start, edge_dst, lgb);
  fused_mid<<<MROWS / 64, 256, 0, stream>>>(lgb, Wt, biasf, awsa, gat);
  edge_kernel<<<MROWS / 4, 256, 0, stream>>>(awsa, gat, row_start, edge_dst, lgb);
  final_out<<<MROWS / 64, 256, 0, stream>>>(lgb, Wt, biasf, awsa, flag, d_out);
}

// Round 4
// 511.587 us; speedup vs baseline: 1.6667x; 1.0453x over previous
//
#include <hip/hip_runtime.h>
#include <hip/hip_bf16.h>

// AttentiveGraph: B=4, N=10000, E=160000, C=F=128, 3 iterations.
// R4: XCD-batch swizzle on count/fill (kill 14x scattered-write amplification
// seen in R3: WRITE_SIZE 72MB for a 5.1MB buffer); conv_obj folded into
// fused_init (reads raw fp32/bf16 objects, converts in-register).

#define BATCH 4
#define NNODE 10000
#define NEDGE 160000
#define TWOE  (2*NEDGE)
#define MROWS (BATCH*NNODE)   // 40000

typedef unsigned short u16;
typedef unsigned int   u32;
typedef unsigned long long u64;
typedef __attribute__((ext_vector_type(8))) short bf16x8_t;
typedef __attribute__((ext_vector_type(4))) float f32x4_t;

__device__ __forceinline__ float b2f(u16 h){ return __uint_as_float(((u32)h) << 16); }
__device__ __forceinline__ u16 f2bf(float f){
  u32 u = __float_as_uint(f);
  return (u16)((u + 0x7fffu + ((u >> 16) & 1u)) >> 16);   // RNE
}
__device__ __forceinline__ float fast_tanh(float x){
  float e = __expf(2.0f * x);
  return fmaf(-2.0f, __builtin_amdgcn_rcpf(e + 1.0f), 1.0f);
}

// ---------------- storage dtype probe (fp32 vs bf16 storage) ------------------
__global__ void detect_dtype(const u32* __restrict__ objw, int* __restrict__ flag){
  __shared__ int zc, hc;
  if (threadIdx.x == 0){ zc = 0; hc = 0; }
  __syncthreads();
  int z = 0, h = 0;
  for (int i = threadIdx.x; i < 1024; i += 256){
    u32 lo = objw[i] & 0xffffu;
    if (lo == 0) z++;
    if (((lo >> 7) & 0xffu) >= 160u) h++;
  }
  atomicAdd(&zc, z); atomicAdd(&hc, h);
  __syncthreads();
  if (threadIdx.x == 0) *flag = (hc > 0 || zc > 512) ? 1 : 0;   // 1 = fp32 storage
}

// Wt[m][c*128+k] = W_m[k*128+c]; tail block converts biases.
__global__ void prep_weights(const void* __restrict__ Wo, const void* __restrict__ Wa,
                             const void* __restrict__ Wla, const void* __restrict__ Wl,
                             const void* __restrict__ ab, const void* __restrict__ sb,
                             const int* __restrict__ flag, u16* __restrict__ Wt,
                             float* __restrict__ biasf){
  int idx = blockIdx.x * 256 + threadIdx.x;
  bool f = (*flag != 0);
  if (idx < 65536){
    int m = idx >> 14, k = (idx >> 7) & 127, c = idx & 127;
    const void* src = (m == 0) ? Wo : (m == 1) ? Wa : (m == 2) ? Wla : Wl;
    u16 h = f ? f2bf(((const float*)src)[k * 128 + c]) : ((const u16*)src)[k * 128 + c];
    Wt[m * 16384 + c * 128 + k] = h;
  } else {
    int t = idx - 65536;                     // 0..255
    const void* src = (t < 128) ? sb : ab;
    int i = t & 127;
    biasf[t] = f ? ((const float*)src)[i] : b2f(((const u16*)src)[i]);
  }
}

// ---------------- CSR build (XCD-batch swizzled) -------------------------------
// blockIdx%8 -> XCD (round-robin dispatch); batch = XCD/2 keeps each batch's
// counts/cursor/edge_dst slab resident+dirty in one XCD-pair's L2 only.
__device__ __forceinline__ bool swiz_edge(int g, int tid, int& b, int& e){
  int xcd = g & 7;
  b = xcd >> 1;
  int j = ((g >> 3) << 1) | (xcd & 1);    // 0..625
  e = j * 256 + tid;
  return e < NEDGE;
}

__global__ void count_edges(const int* __restrict__ conn, int* __restrict__ counts){
  int b, e;
  if (!swiz_edge(blockIdx.x, threadIdx.x, b, e)) return;
  int2 c = ((const int2*)conn)[(size_t)b * NEDGE + e];
  atomicAdd(&counts[b * NNODE + c.x], 1);
  atomicAdd(&counts[b * NNODE + c.y], 1);
}

// scanA: per 256-node chunk local exclusive scan + chunk totals. 160 blocks.
__global__ void scanA(const int* __restrict__ counts, int* __restrict__ row_start,
                      int* __restrict__ bsum){
  int b = blockIdx.x / 40, j = blockIdx.x % 40;
  int n = j * 256 + threadIdx.x;
  __shared__ int buf[256];
  int v = (n < NNODE) ? counts[b * NNODE + n] : 0;
  buf[threadIdx.x] = v;
  __syncthreads();
  for (int off = 1; off < 256; off <<= 1){
    int x = (threadIdx.x >= (unsigned)off) ? buf[threadIdx.x - off] : 0;
    __syncthreads();
    buf[threadIdx.x] += x;
    __syncthreads();
  }
  int incl = buf[threadIdx.x];
  if (n < NNODE) row_start[b * (NNODE + 1) + n] = incl - v;
  if (threadIdx.x == 255) bsum[blockIdx.x] = incl;
}

__global__ void scanB(const int* __restrict__ bsum, int* __restrict__ boff,
                      int* __restrict__ row_start){
  __shared__ int s[160];
  if (threadIdx.x < 160) s[threadIdx.x] = bsum[threadIdx.x];
  __syncthreads();
  if (threadIdx.x < 160){
    int b = threadIdx.x / 40, j = threadIdx.x % 40;
    int off = 0;
    for (int q = b * 40; q < b * 40 + j; q++) off += s[q];
    boff[threadIdx.x] = off;
  }
  if (threadIdx.x < BATCH) row_start[threadIdx.x * (NNODE + 1) + NNODE] = TWOE;
}

__global__ void scanC(int* __restrict__ row_start, const int* __restrict__ boff,
                      int* __restrict__ cursor){
  int b = blockIdx.x / 40, j = blockIdx.x % 40;
  int n = j * 256 + threadIdx.x;
  if (n < NNODE){
    int idx = b * (NNODE + 1) + n;
    int r = row_start[idx] + boff[blockIdx.x];
    row_start[idx] = r;
    cursor[b * NNODE + n] = r;
  }
}

__global__ void fill_edges(const int* __restrict__ conn, int* __restrict__ cursor,
                           int* __restrict__ edge_dst){
  int b, e;
  if (!swiz_edge(blockIdx.x, threadIdx.x, b, e)) return;
  int2 c = ((const int2*)conn)[(size_t)b * NEDGE + e];
  int p1 = atomicAdd(&cursor[b * NNODE + c.x], 1);
  edge_dst[(size_t)b * TWOE + p1] = c.y;
  int p2 = atomicAdd(&cursor[b * NNODE + c.y], 1);
  edge_dst[(size_t)b * TWOE + p2] = c.x;
}

// ---------------- MFMA helpers (wave = 16 rows x 128 cols) --------------------
__device__ __forceinline__ void gemm_tile(const u16* __restrict__ arow,
    const u16* __restrict__ wt, int lm, int lq, f32x4_t acc[8]){
  #pragma unroll
  for (int ks = 0; ks < 4; ks++){
    bf16x8_t a = *(const bf16x8_t*)(arow + ks * 32);
    #pragma unroll
    for (int nb = 0; nb < 8; nb++){
      bf16x8_t bfr = *(const bf16x8_t*)(wt + (nb * 16 + lm) * 128 + ks * 32 + lq * 8);
      acc[nb] = __builtin_amdgcn_mfma_f32_16x16x32_bf16(a, bfr, acc[nb], 0, 0, 0);
    }
  }
}

// phase 2: states tile (LDS, A-layout) -> aW (fp32) + EL (gat slot)
__device__ __forceinline__ void phase2_awlaw(const u16* __restrict__ ldsrow,
    const u16* __restrict__ Wt, const float* __restrict__ biasf,
    int lm, int lq, int r0, float* __restrict__ awsa, u16* __restrict__ gat){
  const u16* Wta  = Wt + 16384;
  const u16* Wtla = Wt + 32768;
  f32x4_t accA[8], accL[8];
  #pragma unroll
  for (int i = 0; i < 8; i++){ accA[i] = (f32x4_t){0.f,0.f,0.f,0.f}; accL[i] = (f32x4_t){0.f,0.f,0.f,0.f}; }
  #pragma unroll
  for (int ks = 0; ks < 4; ks++){
    bf16x8_t a = *(const bf16x8_t*)(ldsrow + ks * 32);
    #pragma unroll
    for (int nb = 0; nb < 8; nb++){
      bf16x8_t ba = *(const bf16x8_t*)(Wta  + (nb * 16 + lm) * 128 + ks * 32 + lq * 8);
      bf16x8_t bl = *(const bf16x8_t*)(Wtla + (nb * 16 + lm) * 128 + ks * 32 + lq * 8);
      accA[nb] = __builtin_amdgcn_mfma_f32_16x16x32_bf16(a, ba, accA[nb], 0, 0, 0);
      accL[nb] = __builtin_amdgcn_mfma_f32_16x16x32_bf16(a, bl, accL[nb], 0, 0, 0);
    }
  }
  #pragma unroll
  for (int nb = 0; nb < 8; nb++){
    int col = nb * 16 + lm;
    float bb = biasf[128 + col];
    #pragma unroll
    for (int i = 0; i < 4; i++){
      int row = r0 + lq * 4 + i;
      awsa[(size_t)row * 128 + col] = accA[nb][i];
      gat[(size_t)row * 256 + (col >> 1) * 4 + (col & 1)] = f2bf(__expf(accL[nb][i] + bb));
    }
  }
}

// init: states = tanh(obj@Wo + b) reading raw objects (fp32 or bf16); then aW/EL.
__global__ void __launch_bounds__(256) fused_init(const void* __restrict__ obj_raw,
    const int* __restrict__ flag, const u16* __restrict__ Wt,
    const float* __restrict__ biasf, float* __restrict__ awsa, u16* __restrict__ gat){
  __shared__ u16 lds[4][16][136];
  const int lane = threadIdx.x & 63, wave = threadIdx.x >> 6;
  const int r0 = blockIdx.x * 64 + wave * 16;
  const int lm = lane & 15, lq = lane >> 4;
  f32x4_t acc[8];
  #pragma unroll
  for (int i = 0; i < 8; i++) acc[i] = (f32x4_t){0.f, 0.f, 0.f, 0.f};
  if (*flag){
    const float* arow = (const float*)obj_raw + (size_t)(r0 + lm) * 128 + lq * 8;
    #pragma unroll
    for (int ks = 0; ks < 4; ks++){
      float4 fa = *(const float4*)(arow + ks * 32);
      float4 fb = *(const float4*)(arow + ks * 32 + 4);
      bf16x8_t a;
      a[0] = (short)f2bf(fa.x); a[1] = (short)f2bf(fa.y);
      a[2] = (short)f2bf(fa.z); a[3] = (short)f2bf(fa.w);
      a[4] = (short)f2bf(fb.x); a[5] = (short)f2bf(fb.y);
      a[6] = (short)f2bf(fb.z); a[7] = (short)f2bf(fb.w);
      #pragma unroll
      for (int nb = 0; nb < 8; nb++){
        bf16x8_t bfr = *(const bf16x8_t*)(Wt + (nb * 16 + lm) * 128 + ks * 32 + lq * 8);
        acc[nb] = __builtin_amdgcn_mfma_f32_16x16x32_bf16(a, bfr, acc[nb], 0, 0, 0);
      }
    }
  } else {
    gemm_tile((const u16*)obj_raw + (size_t)(r0 + lm) * 128 + lq * 8, Wt, lm, lq, acc);
  }
  #pragma unroll
  for (int nb = 0; nb < 8; nb++){
    int col = nb * 16 + lm;
    float bb = biasf[col];
    #pragma unroll
    for (int i = 0; i < 4; i++){
      int row = r0 + lq * 4 + i;
      u16 h = f2bf(fast_tanh(acc[nb][i] + bb));
      gat[(size_t)row * 256 + (col >> 1) * 4 + 2 + (col & 1)] = h;   // S slot
      lds[wave][lq * 4 + i][col] = h;
    }
  }
  __syncthreads();
  phase2_awlaw(&lds[wave][lm][lq * 8], Wt, biasf, lm, lq, r0, awsa, gat);
}

// mid: states = tanh(sa + lgb@Wl + b); then aW/EL for next iter.
__global__ void __launch_bounds__(256) fused_mid(const u16* __restrict__ lgb,
    const u16* __restrict__ Wt, const float* __restrict__ biasf,
    float* __restrict__ awsa, u16* __restrict__ gat){
  __shared__ u16 lds[4][16][136];
  const int lane = threadIdx.x & 63, wave = threadIdx.x >> 6;
  const int r0 = blockIdx.x * 64 + wave * 16;
  const int lm = lane & 15, lq = lane >> 4;
  const _Float16* sah = (const _Float16*)awsa;   // fp16 sa in back half of aW rows
  f32x4_t acc[8];
  #pragma unroll
  for (int i = 0; i < 8; i++) acc[i] = (f32x4_t){0.f, 0.f, 0.f, 0.f};
  gemm_tile(lgb + (size_t)(r0 + lm) * 128 + lq * 8, Wt + 49152, lm, lq, acc);
  #pragma unroll
  for (int nb = 0; nb < 8; nb++){
    int col = nb * 16 + lm;
    float bb = biasf[col];
    #pragma unroll
    for (int i = 0; i < 4; i++){
      int row = r0 + lq * 4 + i;
      float sa = (float)sah[(size_t)row * 256 + 128 + col];
      u16 h = f2bf(fast_tanh(sa + acc[nb][i] + bb));
      gat[(size_t)row * 256 + (col >> 1) * 4 + 2 + (col & 1)] = h;   // S slot
      lds[wave][lq * 4 + i][col] = h;
    }
  }
  __syncthreads();
  phase2_awlaw(&lds[wave][lm][lq * 8], Wt, biasf, lm, lq, r0, awsa, gat);
}

// final: out = tanh(sa + lgb@Wl + b), fp32 or bf16 per flag.
__global__ void __launch_bounds__(256) final_out(const u16* __restrict__ lgb,
    const u16* __restrict__ Wt, const float* __restrict__ biasf,
    const float* __restrict__ awsa, const int* __restrict__ flag,
    void* __restrict__ outp){
  const int lane = threadIdx.x & 63, wave = threadIdx.x >> 6;
  const int r0 = blockIdx.x * 64 + wave * 16;
  const int lm = lane & 15, lq = lane >> 4;
  const _Float16* sah = (const _Float16*)awsa;
  bool f32out = (*flag != 0);
  f32x4_t acc[8];
  #pragma unroll
  for (int i = 0; i < 8; i++) acc[i] = (f32x4_t){0.f, 0.f, 0.f, 0.f};
  gemm_tile(lgb + (size_t)(r0 + lm) * 128 + lq * 8, Wt + 49152, lm, lq, acc);
  #pragma unroll
  for (int nb = 0; nb < 8; nb++){
    int col = nb * 16 + lm;
    float bb = biasf[col];
    #pragma unroll
    for (int i = 0; i < 4; i++){
      int row = r0 + lq * 4 + i;
      float sa = (float)sah[(size_t)row * 256 + 128 + col];
      float v = fast_tanh(sa + acc[nb][i] + bb);
      if (f32out) ((float*)outp)[(size_t)row * 128 + col] = v;
      else        ((u16*)  outp)[(size_t)row * 128 + col] = f2bf(v);
    }
  }
}

// ---------------- edge gather: 1 wave/node, x8 unroll, XCD-batch swizzle ------
__device__ __forceinline__ void acc_edge(uint2 g, float& s1x, float& s1y,
                                         float& s2x, float& s2y){
  float el0 = __uint_as_float(g.x << 16);
  float el1 = __uint_as_float(g.x & 0xffff0000u);
  float sv0 = __uint_as_float(g.y << 16);
  float sv1 = __uint_as_float(g.y & 0xffff0000u);
  s1x += el0; s1y += el1;
  s2x = fmaf(el0, sv0, s2x);
  s2y = fmaf(el1, sv1, s2y);
}

__global__ void __launch_bounds__(256) edge_kernel(float* __restrict__ awsa,
    const u16* __restrict__ gat, const int* __restrict__ row_start,
    const int* __restrict__ edge_dst, u16* __restrict__ lgb){
  int g = blockIdx.x;
  int xcd = g & 7;
  int b = xcd >> 1;
  int i = ((g >> 3) << 1) | (xcd & 1);            // 0..2499 per batch
  int n = i * 4 + (int)(threadIdx.x >> 6);
  int node = b * NNODE + n;
  int lane = threadIdx.x & 63;
  int e0 = __builtin_amdgcn_readfirstlane(row_start[b * (NNODE + 1) + n]);
  int e1 = __builtin_amdgcn_readfirstlane(row_start[b * (NNODE + 1) + n + 1]);
  const int* ed = edge_dst + (size_t)b * TWOE;
  const u16* gatb = gat + (size_t)b * NNODE * 256;

  float2 aw = *(const float2*)(awsa + (size_t)node * 128 + 2 * lane);
  float ea0 = __expf(aw.x), ea1 = __expf(aw.y);
  float s1x = 0.f, s1y = 0.f, s2x = 0.f, s2y = 0.f;
  float t1x = 0.f, t1y = 0.f, t2x = 0.f, t2y = 0.f;
  int e = e0;
  for (; e + 8 <= e1; e += 8){
    int d0 = ed[e+0], d1 = ed[e+1], d2 = ed[e+2], d3 = ed[e+3];
    int d4 = ed[e+4], d5 = ed[e+5], d6 = ed[e+6], d7 = ed[e+7];
    uint2 g0 = *(const uint2*)(gatb + (size_t)d0 * 256 + lane * 4);
    uint2 g1 = *(const uint2*)(gatb + (size_t)d1 * 256 + lane * 4);
    uint2 g2 = *(const uint2*)(gatb + (size_t)d2 * 256 + lane * 4);
    uint2 g3 = *(const uint2*)(gatb + (size_t)d3 * 256 + lane * 4);
    uint2 g4 = *(const uint2*)(gatb + (size_t)d4 * 256 + lane * 4);
    uint2 g5 = *(const uint2*)(gatb + (size_t)d5 * 256 + lane * 4);
    uint2 g6 = *(const uint2*)(gatb + (size_t)d6 * 256 + lane * 4);
    uint2 g7 = *(const uint2*)(gatb + (size_t)d7 * 256 + lane * 4);
    acc_edge(g0, s1x, s1y, s2x, s2y); acc_edge(g1, t1x, t1y, t2x, t2y);
    acc_edge(g2, s1x, s1y, s2x, s2y); acc_edge(g3, t1x, t1y, t2x, t2y);
    acc_edge(g4, s1x, s1y, s2x, s2y); acc_edge(g5, t1x, t1y, t2x, t2y);
    acc_edge(g6, s1x, s1y, s2x, s2y); acc_edge(g7, t1x, t1y, t2x, t2y);
  }
  for (; e < e1; e++){
    int d = ed[e];
    uint2 gg = *(const uint2*)(gatb + (size_t)d * 256 + lane * 4);
    acc_edge(gg, s1x, s1y, s2x, s2y);
  }
  s1x += t1x; s1y += t1y; s2x += t2x; s2y += t2y;
  float inv0 = __builtin_amdgcn_rcpf(fmaf(ea0, s1x, 1.0f));
  float inv1 = __builtin_amdgcn_rcpf(fmaf(ea1, s1y, 1.0f));
  float lg0 = ea0 * s2x * inv0;
  float lg1 = ea1 * s2y * inv1;
  u32 sp = *(const u32*)((const u16*)gat + (size_t)node * 256 + lane * 4 + 2);
  float s0 = __uint_as_float(sp << 16);
  float s1 = __uint_as_float(sp & 0xffff0000u);
  _Float16 h0 = (_Float16)(s0 * inv0);
  _Float16 h1 = (_Float16)(s1 * inv1);
  u32 pk = (u32)(*(const u16*)&h0) | ((u32)(*(const u16*)&h1) << 16);
  ((u32*)awsa)[(size_t)node * 128 + 64 + lane] = pk;              // sa fp16, back half
  ((u32*)lgb)[(size_t)node * 64 + lane] = (u32)f2bf(lg0) | ((u32)f2bf(lg1) << 16);
}

// ---------------- host launcher ----------------------------------------------
extern "C" void kernel_launch(void* const* d_in, const int* in_sizes, int n_in,
                              void* d_out, int out_size, void* d_ws, size_t ws_size,
                              hipStream_t stream){
  (void)in_sizes; (void)n_in; (void)ws_size; (void)out_size;
  const void* objects = d_in[0];
  const void* Wo      = d_in[1];
  const void* Wa      = d_in[2];
  const void* Wla     = d_in[3];
  const void* attn_b  = d_in[4];
  const void* Wl      = d_in[5];
  const void* state_b = d_in[6];
  const int*  conn    = (const int*)d_in[7];

  char* base = (char*)d_ws;
  size_t off = 0;
  auto alloc = [&](size_t bytes) -> char* {
    char* p = base + off;
    off = (off + bytes + 255) & ~(size_t)255;
    return p;
  };
  int*   flag      = (int*)  alloc(256);
  u16*   Wt        = (u16*)  alloc((size_t)4 * 16384 * 2);
  float* biasf     = (float*)alloc(256 * 4);
  float* awsa      = (float*)alloc((size_t)MROWS * 128 * 4);   // aW fp32; sa fp16 overlay
  u16*   gat       = (u16*)  alloc((size_t)MROWS * 512);       // {EL pair, S pair} / lane
  u16*   lgb       = (u16*)  alloc((size_t)MROWS * 128 * 2);
  int*   counts    = (int*)  alloc((size_t)MROWS * 4);
  int*   cursor    = (int*)  alloc((size_t)MROWS * 4);
  int*   row_start = (int*)  alloc((size_t)BATCH * (NNODE + 1) * 4);
  int*   edge_dst  = (int*)  alloc((size_t)BATCH * TWOE * 4);
  int*   bsum      = (int*)  alloc(160 * 4);
  int*   boff      = (int*)  alloc(160 * 4);

  detect_dtype<<<1, 256, 0, stream>>>((const u32*)objects, flag);
  prep_weights<<<257, 256, 0, stream>>>(Wo, Wa, Wla, Wl, attn_b, state_b, flag, Wt, biasf);

  hipMemsetAsync(counts, 0, (size_t)MROWS * 4, stream);
  count_edges<<<2504, 256, 0, stream>>>(conn, counts);
  scanA<<<160, 256, 0, stream>>>(counts, row_start, bsum);
  scanB<<<1, 256, 0, stream>>>(bsum, boff, row_start);
  scanC<<<160, 256, 0, stream>>>(row_start, boff, cursor);
  fill_edges<<<2504, 256, 0, stream>>>(conn, cursor, edge_dst);

  fused_init<<<MROWS / 64, 256, 0, stream>>>(objects, flag, Wt, biasf, awsa, gat);
  edge_kernel<<<MROWS / 4, 256, 0, stream>>>(awsa, gat, row_start, edge_dst, lgb);
  fused_mid<<<MROWS / 64, 256, 0, stream>>>(lgb, Wt, biasf, awsa, gat);
  edge_kernel<<<MROWS / 4, 256, 0, stream>>>(awsa, gat, row_start, edge_dst, lgb);
  fused_mid<<<MROWS / 64, 256, 0, stream>>>(lgb, Wt, biasf, awsa, gat);
  edge_kernel<<<MROWS / 4, 256, 0, stream>>>(awsa, gat, row_start, edge_dst, lgb);
  final_out<<<MROWS / 64, 256, 0, stream>>>(lgb, Wt, biasf, awsa, flag, d_out);
}